// Round 11
// baseline (153.483 us; speedup 1.0000x reference)
//
#include <hip/hip_runtime.h>

#define EHUGE (-(1 << 28))
constexpr float INV_LN2 = 1.4426950408889634f;
constexpr float LN2f    = 0.6931471805599453f;

// ---------------- Phase 1: ND[b][r][e] f16, stride 516 elems ----------------
// Row r holds nd(r,jy) = -|x_r - y_jy|^2/ln2 at elem e = jy + (r&3); e outside
// [r&3, 511+(r&3)] = -60000 guards. Lane owns column jy (y in regs); waves
// split rows; x rows read from LDS via uniform-address (broadcast) ds_read.
__global__ __launch_bounds__(256) void dist_kernel(
    const float* __restrict__ X, const float* __restrict__ Y,
    unsigned short* __restrict__ ND)
{
  const int b  = blockIdx.x;
  const int jg = blockIdx.y;            // 8 j-groups of 64
  const int t  = threadIdx.x;
  const int wv = t >> 6, lane = t & 63;
  const int jy = 64 * jg + lane;

  __shared__ float4 xsh4[2048];         // x rows, 32 KB
  __shared__ float  x2sh[512];

  const float*  xb  = X + (size_t)b * 8192;
  const float4* xb4 = (const float4*)xb;
  const float*  yb  = Y + (size_t)b * 8192;

  for (int i = t; i < 2048; i += 256) xsh4[i] = xb4[i];

  // x2 for rows 2t, 2t+1 (from global, no LDS dep)
  {
    const float4* p = (const float4*)(xb + (size_t)(2 * t) * 16);
    float4 a0=p[0],a1=p[1],a2=p[2],a3=p[3], c0=p[4],c1=p[5],c2=p[6],c3=p[7];
    float sa = 0.f, sc = 0.f;
    sa=fmaf(a0.x,a0.x,sa); sa=fmaf(a0.y,a0.y,sa); sa=fmaf(a0.z,a0.z,sa); sa=fmaf(a0.w,a0.w,sa);
    sa=fmaf(a1.x,a1.x,sa); sa=fmaf(a1.y,a1.y,sa); sa=fmaf(a1.z,a1.z,sa); sa=fmaf(a1.w,a1.w,sa);
    sa=fmaf(a2.x,a2.x,sa); sa=fmaf(a2.y,a2.y,sa); sa=fmaf(a2.z,a2.z,sa); sa=fmaf(a2.w,a2.w,sa);
    sa=fmaf(a3.x,a3.x,sa); sa=fmaf(a3.y,a3.y,sa); sa=fmaf(a3.z,a3.z,sa); sa=fmaf(a3.w,a3.w,sa);
    sc=fmaf(c0.x,c0.x,sc); sc=fmaf(c0.y,c0.y,sc); sc=fmaf(c0.z,c0.z,sc); sc=fmaf(c0.w,c0.w,sc);
    sc=fmaf(c1.x,c1.x,sc); sc=fmaf(c1.y,c1.y,sc); sc=fmaf(c1.z,c1.z,sc); sc=fmaf(c1.w,c1.w,sc);
    sc=fmaf(c2.x,c2.x,sc); sc=fmaf(c2.y,c2.y,sc); sc=fmaf(c2.z,c2.z,sc); sc=fmaf(c2.w,c2.w,sc);
    sc=fmaf(c3.x,c3.x,sc); sc=fmaf(c3.y,c3.y,sc); sc=fmaf(c3.z,c3.z,sc); sc=fmaf(c3.w,c3.w,sc);
    x2sh[2 * t] = sa; x2sh[2 * t + 1] = sc;
  }

  // y column into regs
  float yv[16]; float y2 = 0.f;
  {
    const float4* p = (const float4*)(yb + (size_t)jy * 16);
    float4 v0 = p[0], v1 = p[1], v2 = p[2], v3 = p[3];
    yv[0]=v0.x; yv[1]=v0.y; yv[2]=v0.z; yv[3]=v0.w;
    yv[4]=v1.x; yv[5]=v1.y; yv[6]=v1.z; yv[7]=v1.w;
    yv[8]=v2.x; yv[9]=v2.y; yv[10]=v2.z; yv[11]=v2.w;
    yv[12]=v3.x; yv[13]=v3.y; yv[14]=v3.z; yv[15]=v3.w;
    #pragma unroll
    for (int q = 0; q < 16; ++q) y2 = fmaf(yv[q], yv[q], y2);
  }
  __syncthreads();

  unsigned short* nb = ND + (size_t)b * 512 * 516;
  const float* xsf = (const float*)xsh4;

  for (int rr = 0; rr < 128; rr += 2) {
    const int r = 128 * wv + rr;
    const float4* xr4 = &xsh4[(size_t)r * 4];
    float4 a0 = xr4[0], a1 = xr4[1], a2 = xr4[2], a3 = xr4[3];
    float4 c0 = xr4[4], c1 = xr4[5], c2 = xr4[6], c3 = xr4[7];
    float xa[16] = { a0.x,a0.y,a0.z,a0.w, a1.x,a1.y,a1.z,a1.w,
                     a2.x,a2.y,a2.z,a2.w, a3.x,a3.y,a3.z,a3.w };
    float xc[16] = { c0.x,c0.y,c0.z,c0.w, c1.x,c1.y,c1.z,c1.w,
                     c2.x,c2.y,c2.z,c2.w, c3.x,c3.y,c3.z,c3.w };
    float d0 = 0.f, d1 = 0.f;
    #pragma unroll
    for (int q = 0; q < 16; ++q) {
      d0 = fmaf(xa[q], yv[q], d0);
      d1 = fmaf(xc[q], yv[q], d1);
    }
    const float nd0 = (2.f * d0 - x2sh[r]     - y2) * INV_LN2;
    const float nd1 = (2.f * d1 - x2sh[r + 1] - y2) * INV_LN2;
    nb[(size_t)r * 516 + jy + (r & 3)]             = __builtin_bit_cast(unsigned short, (_Float16)nd0);
    nb[(size_t)(r + 1) * 516 + jy + ((r + 1) & 3)] = __builtin_bit_cast(unsigned short, (_Float16)nd1);
  }
  (void)xsf;

  // guard elems: only one block per batch writes them
  if (jg == 0) {
    const unsigned short G = __builtin_bit_cast(unsigned short, (_Float16)(-60000.0f));
    #pragma unroll
    for (int rr2 = 0; rr2 < 2; ++rr2) {
      const int r = 2 * t + rr2, sh = r & 3;
      unsigned short* rowp = nb + (size_t)r * 516;
      #pragma unroll
      for (int k = 0; k < 4; ++k) {
        const int e = (k < sh) ? k : 512 + k;
        rowp[e] = G;
      }
    }
  }
}

// ---------------- Phase 2: (q,E)-domain wavefront DP, 8-wave pipeline ----------------
// V(r,j) = 2^{-r'} stored as q*2^E. Cell: Em = max3(E); sum of 3 ldexp'd q;
// n = exp2(frac(nd)) * sum; renorm by exponent-bit extract; E += floor(nd).
// All-ALU chain (~35 cy); the exp2 is off-chain. Schedule = r10 verbatim
// (PASSED, absmax 0): wave w rows 64w+1..64w+64, lane l row 64w+l+1, col
// j = t-l; DPP wf_sr1 cross-lane; LDS ring lag-5 phases of K=16; guarded
// edge phases pw<4 / pw>=32; 15-step peel; lgkm-only phase barrier.
template<bool PRE>
__global__ __launch_bounds__(512, 1) void dp_kernel(
    const unsigned short* __restrict__ ND, const float* __restrict__ X,
    const float* __restrict__ Y, float* __restrict__ out)
{
  const int b   = blockIdx.x;
  const int tid = threadIdx.x;
  const int w   = tid >> 6;
  const int l   = tid & 63;
  const int r   = 64 * w + l;

  __shared__ alignas(16) float ring_q[7][64];
  __shared__ alignas(16) int   ring_E[7][64];

  float Pq  = 0.f;            int PE  = EHUGE;     // V(r+1, j-1)
  float dgq = (w == 0 && l == 0) ? 1.f : 0.f;      // V(r, j-1); corner V(0,0)=1
  int   dgE = (w == 0 && l == 0) ? 0   : EHUGE;
  const bool doring = (l == 63) && (w < 7);
  const int  lq = l >> 2;

  const uint2* rp = nullptr;
  uint2 cur0, cur1, cur2, cur3, nxt0, nxt1, nxt2, nxt3;
  float xr0[16];
  float x2 = 0.f;
  const float4* yb4 = (const float4*)(Y + (size_t)b * 8192);

  if constexpr (PRE) {
    rp = (const uint2*)(ND + ((size_t)b * 512 + (size_t)r) * 516);
    cur0 = rp[min(max(0 - lq, 0), 128)];
    cur1 = rp[min(max(1 - lq, 0), 128)];
    cur2 = rp[min(max(2 - lq, 0), 128)];
    cur3 = rp[min(max(3 - lq, 0), 128)];
  } else {
    const float4* px = (const float4*)(X + ((size_t)b * 512 + r) * 16);
    float4 u0 = px[0], u1 = px[1], u2 = px[2], u3 = px[3];
    float tv[16] = { u0.x,u0.y,u0.z,u0.w, u1.x,u1.y,u1.z,u1.w,
                     u2.x,u2.y,u2.z,u2.w, u3.x,u3.y,u3.z,u3.w };
    #pragma unroll
    for (int q = 0; q < 16; ++q) { xr0[q] = tv[q]; x2 = fmaf(tv[q], tv[q], x2); }
  }

#define DPCELL(K, NDV, RQV, REV, GUARDED)                                      \
  {                                                                            \
    const float nd_ = (NDV);                                                   \
    const float f_  = floorf(nd_);                                             \
    const float e_  = __builtin_amdgcn_exp2f(nd_ - f_);                        \
    const int  nI_  = (int)f_;                                                 \
    const int sq_ = __builtin_amdgcn_update_dpp(__builtin_bit_cast(int, Pq),   \
        __builtin_bit_cast(int, Pq), 0x138, 0xF, 0xF, false);                  \
    const int sE_ = __builtin_amdgcn_update_dpp(PE, PE, 0x138, 0xF, 0xF, false); \
    float upq_ = __builtin_bit_cast(float, sq_);                               \
    int   upE_ = sE_;                                                          \
    if (l == 0) { upq_ = (w == 0) ? 0.f : (RQV); upE_ = (w == 0) ? EHUGE : (REV); } \
    const int Em_ = max(max(dgE, upE_), PE);                                   \
    const float s_ = ldexpf(dgq, dgE - Em_) + ldexpf(upq_, upE_ - Em_)         \
                   + ldexpf(Pq, PE - Em_);                                     \
    const float n_ = e_ * s_;                                                  \
    const int  x_  = (int)(__builtin_bit_cast(unsigned, n_) >> 23) - 126;      \
    float qn_ = ldexpf(n_, -x_);                                               \
    int   En_ = (Em_ + x_) + nI_;                                              \
    if (GUARDED) {                                                             \
      const bool v_ = (unsigned)(tml + (K)) < 512u;                            \
      qn_ = v_ ? qn_ : 0.f;                                                    \
      En_ = v_ ? En_ : EHUGE;                                                  \
    }                                                                          \
    dgq = upq_; dgE = upE_;                                                    \
    Pq = qn_; PE = En_;                                                        \
    if (doring) {                                                              \
      ring_q[w][(tb64 + (K)) & 63] = qn_;                                      \
      ring_E[w][(tb64 + (K)) & 63] = En_;                                      \
    }                                                                          \
  }

#define DPSTEP(K, DW, HI, RQV, REV, GUARDED)                                   \
  {                                                                            \
    if constexpr (PRE) {                                                       \
      const float ndp_ = (float)__builtin_bit_cast(_Float16,                   \
          (unsigned short)((HI) ? ((DW) >> 16) : ((DW) & 0xffffu)));           \
      DPCELL(K, ndp_, RQV, REV, GUARDED)                                       \
    } else {                                                                   \
      const int jy_ = tml + (K);                                               \
      const int jc_ = min(max(jy_, 0), 511);                                   \
      float4 q0 = yb4[4*jc_+0], q1 = yb4[4*jc_+1],                             \
             q2 = yb4[4*jc_+2], q3 = yb4[4*jc_+3];                             \
      float yv_[16] = { q0.x,q0.y,q0.z,q0.w, q1.x,q1.y,q1.z,q1.w,              \
                        q2.x,q2.y,q2.z,q2.w, q3.x,q3.y,q3.z,q3.w };            \
      float y2_ = 0.f, d0_ = 0.f;                                              \
      _Pragma("unroll")                                                        \
      for (int q = 0; q < 16; ++q) {                                           \
        y2_ = fmaf(yv_[q], yv_[q], y2_);                                       \
        d0_ = fmaf(xr0[q], yv_[q], d0_);                                       \
      }                                                                        \
      const float ndf_ = (2.f * d0_ - x2 - y2_) * INV_LN2;                     \
      DPCELL(K, ndf_, RQV, REV, true)                                          \
    }                                                                          \
  }

#define DP16(G)                                                                \
    DPSTEP(0,  cur0.x, 0, gq0.x, ge0.x, G) DPSTEP(1,  cur0.x, 1, gq0.y, ge0.y, G) \
    DPSTEP(2,  cur0.y, 0, gq0.z, ge0.z, G) DPSTEP(3,  cur0.y, 1, gq0.w, ge0.w, G) \
    DPSTEP(4,  cur1.x, 0, gq1.x, ge1.x, G) DPSTEP(5,  cur1.x, 1, gq1.y, ge1.y, G) \
    DPSTEP(6,  cur1.y, 0, gq1.z, ge1.z, G) DPSTEP(7,  cur1.y, 1, gq1.w, ge1.w, G) \
    DPSTEP(8,  cur2.x, 0, gq2.x, ge2.x, G) DPSTEP(9,  cur2.x, 1, gq2.y, ge2.y, G) \
    DPSTEP(10, cur2.y, 0, gq2.z, ge2.z, G) DPSTEP(11, cur2.y, 1, gq2.w, ge2.w, G) \
    DPSTEP(12, cur3.x, 0, gq3.x, ge3.x, G) DPSTEP(13, cur3.x, 1, gq3.y, ge3.y, G) \
    DPSTEP(14, cur3.y, 0, gq3.z, ge3.z, G) DPSTEP(15, cur3.y, 1, gq3.w, ge3.w, G)

  for (int p = 0; p < 70; ++p) {
    const int pw = p - 5 * w;
    if ((unsigned)pw < 36u) {
      const int tb   = 16 * pw + 1;
      const int tml  = tb - l - 1;
      const int tb64 = tb - 64;
      const int wi   = (w > 0) ? (w - 1) : 0;
      const int rb   = 4 * (pw & 3);
      const float4* rpq = (const float4*)(&ring_q[wi][0]);
      const int4*   rpe = (const int4*)(&ring_E[wi][0]);
      const float4 gq0 = rpq[rb], gq1 = rpq[rb+1], gq2 = rpq[rb+2], gq3 = rpq[rb+3];
      const int4   ge0 = rpe[rb], ge1 = rpe[rb+1], ge2 = rpe[rb+2], ge3 = rpe[rb+3];
      if constexpr (PRE) {
        const int gb = 4 * pw + 4;
        nxt0 = rp[min(max(gb + 0 - lq, 0), 128)];
        nxt1 = rp[min(max(gb + 1 - lq, 0), 128)];
        nxt2 = rp[min(max(gb + 2 - lq, 0), 128)];
        nxt3 = rp[min(max(gb + 3 - lq, 0), 128)];
      }
      if ((unsigned)(pw - 4) < 28u) {
        DP16(false)
      } else {
        DP16(true)
      }
      if constexpr (PRE) { cur0 = nxt0; cur1 = nxt1; cur2 = nxt2; cur3 = nxt3; }
    }
    __builtin_amdgcn_sched_barrier(0);
    asm volatile("s_waitcnt lgkmcnt(0)" ::: "memory");
    __builtin_amdgcn_s_barrier();
    __builtin_amdgcn_sched_barrier(0);
  }

  // peel: wave 7's pw = 35 (tb = 561), steps 561..575 only (skip 576)
  if (w == 7) {
    const int tb   = 561;
    const int tml  = tb - l - 1;
    const int tb64 = tb - 64;
    const int rb   = 4 * (35 & 3);
    const float4* rpq = (const float4*)(&ring_q[6][0]);
    const int4*   rpe = (const int4*)(&ring_E[6][0]);
    const float4 gq0 = rpq[rb], gq1 = rpq[rb+1], gq2 = rpq[rb+2], gq3 = rpq[rb+3];
    const int4   ge0 = rpe[rb], ge1 = rpe[rb+1], ge2 = rpe[rb+2], ge3 = rpe[rb+3];
    DPSTEP(0,  cur0.x, 0, gq0.x, ge0.x, true) DPSTEP(1,  cur0.x, 1, gq0.y, ge0.y, true)
    DPSTEP(2,  cur0.y, 0, gq0.z, ge0.z, true) DPSTEP(3,  cur0.y, 1, gq0.w, ge0.w, true)
    DPSTEP(4,  cur1.x, 0, gq1.x, ge1.x, true) DPSTEP(5,  cur1.x, 1, gq1.y, ge1.y, true)
    DPSTEP(6,  cur1.y, 0, gq1.z, ge1.z, true) DPSTEP(7,  cur1.y, 1, gq1.w, ge1.w, true)
    DPSTEP(8,  cur2.x, 0, gq2.x, ge2.x, true) DPSTEP(9,  cur2.x, 1, gq2.y, ge2.y, true)
    DPSTEP(10, cur2.y, 0, gq2.z, ge2.z, true) DPSTEP(11, cur2.y, 1, gq2.w, ge2.w, true)
    DPSTEP(12, cur3.x, 0, gq3.x, ge3.x, true) DPSTEP(13, cur3.x, 1, gq3.y, ge3.y, true)
    DPSTEP(14, cur3.y, 0, gq3.z, ge3.z, true)
  }
#undef DP16
#undef DPSTEP
#undef DPCELL

  // V(512,512) = Pq * 2^PE ; cost = -ln2 * (log2 q + E)
  if (tid == 511)
    out[b] = -LN2f * (__builtin_amdgcn_logf(Pq) + (float)PE);
}

extern "C" void kernel_launch(void* const* d_in, const int* in_sizes, int n_in,
                              void* d_out, int out_size, void* d_ws, size_t ws_size,
                              hipStream_t stream)
{
  const float* x = (const float*)d_in[0];
  const float* y = (const float*)d_in[1];
  float* o = (float*)d_out;
  const size_t need = (size_t)64 * 512 * 516 * 2;   // 33,816,576 B
  if (ws_size >= need) {
    unsigned short* nd = (unsigned short*)d_ws;
    dist_kernel<<<dim3(64, 8), 256, 0, stream>>>(x, y, nd);
    dp_kernel<true><<<64, 512, 0, stream>>>(nd, x, y, o);
  } else {
    dp_kernel<false><<<64, 512, 0, stream>>>(nullptr, x, y, o);
  }
}